// Round 5
// baseline (640.565 us; speedup 1.0000x reference)
//
#include <hip/hip_runtime.h>
#include <hip/hip_bf16.h>

// Problem constants
#define BB    32
#define NNODE 128
#define INF   64
#define HIDF  128
#define OUTF  64
#define EE    (NNODE*(NNODE-1))   // 16256 edges per batch
#define TILES 127                  // 127 tiles of 128 edges per batch
#define NBLK_EDGE (BB*TILES)       // 4064
#define ROWS_E 520192.0f
#define ROWS_N 4096.0f
#define OUT0_ELEMS (BB*NNODE*OUTF) // 262144
#define H2_ELEMS ((size_t)520192*128)

typedef __bf16 bf16_t;
typedef __bf16 bfrag8 __attribute__((ext_vector_type(8)));
typedef __bf16 bfrag4 __attribute__((ext_vector_type(4)));
typedef float  floatx4 __attribute__((ext_vector_type(4)));

// Dual-dtype helpers: bf=1 -> bf16 buffers, bf=0 -> fp32 buffers
__device__ __forceinline__ float ld_g(const void* p, size_t i, int bf) {
    return bf ? (float)((const bf16_t*)p)[i] : ((const float*)p)[i];
}
__device__ __forceinline__ void st_g(void* p, size_t i, float v, int bf) {
    if (bf) ((bf16_t*)p)[i] = (bf16_t)v; else ((float*)p)[i] = v;
}
__device__ __forceinline__ void* mij_ptr(void* dout, int bf) {
    return bf ? (void*)((bf16_t*)dout + OUT0_ELEMS)
              : (void*)((float*)dout + OUT0_ELEMS);
}
// silu without IEEE division: v_exp + v_add + v_rcp + v_mul.
__device__ __forceinline__ float silu_f(float x) {
    return x * __builtin_amdgcn_rcpf(1.0f + __expf(-x));
}

// LDS tile swizzles (16B-granule XOR involutions)
__device__ __forceinline__ int swz_col(int row, int col)  {   // 128-wide tile
    return col ^ ((row & 15) << 3);
}
__device__ __forceinline__ int swz64_col(int row, int col) {  // 64-wide tile
    return col ^ ((row & 7) << 3);
}

// ---------------------------------------------------------------------------
// K0: prep — detect dtype (eg ones: bf16 pair = 0x3F803F80), zero totE,
// pack W1/W2 into MFMA fragment order: line ((NB*4+ks)*4+q)*16+ln holds
// W[k=ks*32+q*8+j][n=NB*16+ln]; a wave (L=q*16+ln) reads one contiguous
// 1KB line per (NB,ks). This layout is simultaneously a valid B-fragment
// (n = output col) and a valid A-fragment (n = output row) for 16x16x32.
// ---------------------------------------------------------------------------
__global__ __launch_bounds__(256)
void k_prep(const unsigned int* __restrict__ eg_words,
            const void* __restrict__ W1g, const void* __restrict__ W2g,
            bf16_t* __restrict__ Wf1, bf16_t* __restrict__ Wf2,
            int* __restrict__ flag, float* __restrict__ totE)
{
    const int bf = (eg_words[0] == 0x3F803F80u) ? 1 : 0;
    if (blockIdx.x == 0) {
        if (threadIdx.x == 0) *flag = bf;
        totE[threadIdx.x] = 0.f;
    }
    const int idx = blockIdx.x*256 + threadIdx.x;   // 0..32767
    const int mat = idx >> 14;
    const int e   = idx & 16383;                    // e = k*128 + n
    const int n   = e & 127, k = e >> 7;
    const float v = ld_g(mat ? W2g : W1g, e, bf);
    const int NB = n >> 4, ln = n & 15;
    const int ks = k >> 5, q = (k >> 3) & 3, j = k & 7;
    bf16_t* dst = mat ? Wf2 : Wf1;
    dst[((((NB*4 + ks)*4 + q)*16 + ln) << 3) + j] = (bf16_t)v;
}

// ---------------------------------------------------------------------------
// K0c: per-node GEMM1 halves: S[n] = nf[n] @ W1[0:64] + b1,
//                             R[n] = nf[n] @ W1[64:128].
// ef@W1 = S[send]+R[recv]; fp32 outputs keep numerics identical.
// ---------------------------------------------------------------------------
__global__ __launch_bounds__(256)
void k_sr(const void* __restrict__ nf,
          const bf16_t* __restrict__ Wf1, const void* __restrict__ b1g,
          float* __restrict__ Sbuf, float* __restrict__ Rbuf,
          const int* __restrict__ flagp)
{
    __shared__ __align__(16) bf16_t lA[128*64];
    const int bf  = *flagp;
    const int r0  = blockIdx.x * 128;
    const int tid = threadIdx.x;

    // stage nf rows (swizzled, 8 granules/row)
#pragma unroll
    for (int s = 0; s < 4; ++s) {
        const int u = tid + s*256;            // 0..1023
        const int m = u >> 3;
        const int c = (u & 7) ^ (m & 7);
        const size_t gi = (size_t)(r0 + m)*INF + c*8;
        if (bf) {
            ((uint4*)lA)[u] = *(const uint4*)((const bf16_t*)nf + gi);
        } else {
            const float4 f0 = *(const float4*)((const float*)nf + gi);
            const float4 f1 = *(const float4*)((const float*)nf + gi + 4);
            bfrag8 v;
            v[0]=(bf16_t)f0.x; v[1]=(bf16_t)f0.y; v[2]=(bf16_t)f0.z; v[3]=(bf16_t)f0.w;
            v[4]=(bf16_t)f1.x; v[5]=(bf16_t)f1.y; v[6]=(bf16_t)f1.z; v[7]=(bf16_t)f1.w;
            *(bfrag8*)(lA + (size_t)u*8) = v;
        }
    }
    __syncthreads();

    const int w  = tid >> 6;
    const int L  = tid & 63;
    const int wr = w >> 1;
    const int wc = w & 1;
    const int q  = L >> 4;
    const int ln = L & 15;

    const floatx4 zero4 = {0.f, 0.f, 0.f, 0.f};
    floatx4 accS[4][4], accR[4][4];
#pragma unroll
    for (int mt = 0; mt < 4; ++mt)
#pragma unroll
        for (int nt = 0; nt < 4; ++nt) { accS[mt][nt] = zero4; accR[mt][nt] = zero4; }

#pragma unroll
    for (int ks = 0; ks < 2; ++ks) {
        bfrag8 af[4], bs[4], br[4];
#pragma unroll
        for (int mt = 0; mt < 4; ++mt) {
            const int Rr = wr*64 + mt*16 + ln;
            af[mt] = *(const bfrag8*)(lA + Rr*64 + swz64_col(Rr, ks*32 + q*8));
        }
#pragma unroll
        for (int nt = 0; nt < 4; ++nt) {
            bs[nt] = *(const bfrag8*)(Wf1 + ((size_t)((wc*4 + nt)*4 + ks)*64 + L)*8);
            br[nt] = *(const bfrag8*)(Wf1 + ((size_t)((wc*4 + nt)*4 + ks + 2)*64 + L)*8);
        }
#pragma unroll
        for (int mt = 0; mt < 4; ++mt)
#pragma unroll
            for (int nt = 0; nt < 4; ++nt) {
                accS[mt][nt] = __builtin_amdgcn_mfma_f32_16x16x32_bf16(
                    af[mt], bs[nt], accS[mt][nt], 0, 0, 0);
                accR[mt][nt] = __builtin_amdgcn_mfma_f32_16x16x32_bf16(
                    af[mt], br[nt], accR[mt][nt], 0, 0, 0);
            }
    }

#pragma unroll
    for (int nt = 0; nt < 4; ++nt) {
        const int col = wc*64 + nt*16 + ln;
        const float bias = ld_g(b1g, col, bf);
#pragma unroll
        for (int mt = 0; mt < 4; ++mt)
#pragma unroll
            for (int r = 0; r < 4; ++r) {
                const int row = wr*64 + mt*16 + q*4 + r;
                Sbuf[(size_t)(r0 + row)*128 + col] = accS[mt][nt][r] + bias;
                Rbuf[(size_t)(r0 + row)*128 + col] = accR[mt][nt][r];
            }
    }
}

// ---------------------------------------------------------------------------
// K1: edge MLP. h1 tile = silu(S[send]+R[recv]) -> LDS (swizzled); GEMM
// computed OPERAND-SWAPPED: acc[ct][mt] = mfma(W2frag(A), h1frag(B)) so
// D[ch][edge] — each lane holds 4 CONSECUTIVE CHANNELS of one edge, letting
// the epilogue store h2 directly from registers as packed 8B bf16 (no LDS
// round-trip, no scalar ds_writes, one fewer barrier). Stats via ln-butterfly
// shfl + LDS atomics + one global atomic per channel per block.
// ---------------------------------------------------------------------------
__global__ __launch_bounds__(256, 4)
void k_edge_mlp(const float* __restrict__ Sbuf, const float* __restrict__ Rbuf,
                const bf16_t* __restrict__ Wf2, const void* __restrict__ b2g,
                void* __restrict__ dout, bf16_t* __restrict__ h2ws,
                const int* __restrict__ flagp, float* __restrict__ totE,
                int h2mode)
{
    __shared__ __align__(16) bf16_t lA[128*128];   // h1 (swizzled)
    __shared__ float sSum[128], sQ[128];
    const int bf  = *flagp;
    void* h2out = mij_ptr(dout, bf);
    const int bx   = blockIdx.x;
    const int bIdx = bx / TILES;
    const int t    = bx - bIdx*TILES;
    const int tid  = threadIdx.x;

    if (tid < 128) { sSum[tid] = 0.f; sQ[tid] = 0.f; }

    // build h1 tile: granule u (row m, logical granule c) = silu(S+R)
    {
        const size_t nodeBase = (size_t)bIdx*NNODE*128;
#pragma unroll
        for (int s = 0; s < 8; ++s) {
            const int u = tid + s*256;              // 0..2047
            const int m = u >> 4;
            const int c = (u & 15) ^ (m & 15);
            const int eb = t*128 + m;
            const unsigned recv = ((unsigned)eb * 33027u) >> 22;   // eb/127
            const unsigned rr   = (unsigned)eb - recv*127u;
            const unsigned send = rr + (rr >= recv ? 1u : 0u);
            const float* Sp = Sbuf + nodeBase + (size_t)send*128 + c*8;
            const float* Rp = Rbuf + nodeBase + (size_t)recv*128 + c*8;
            const float4 s0 = *(const float4*)Sp;
            const float4 s1 = *(const float4*)(Sp + 4);
            const float4 r0v = *(const float4*)Rp;
            const float4 r1v = *(const float4*)(Rp + 4);
            bfrag8 v;
            v[0]=(bf16_t)silu_f(s0.x + r0v.x); v[1]=(bf16_t)silu_f(s0.y + r0v.y);
            v[2]=(bf16_t)silu_f(s0.z + r0v.z); v[3]=(bf16_t)silu_f(s0.w + r0v.w);
            v[4]=(bf16_t)silu_f(s1.x + r1v.x); v[5]=(bf16_t)silu_f(s1.y + r1v.y);
            v[6]=(bf16_t)silu_f(s1.z + r1v.z); v[7]=(bf16_t)silu_f(s1.w + r1v.w);
            *(bfrag8*)(lA + (size_t)u*8) = v;
        }
    }
    __syncthreads();

    const int w  = tid >> 6;
    const int L  = tid & 63;
    const int wr = w >> 1;     // edge 64-group
    const int wc = w & 1;      // channel 64-group
    const int q  = L >> 4;
    const int ln = L & 15;

    const floatx4 zero4 = {0.f, 0.f, 0.f, 0.f};
    floatx4 acc[4][4];         // [ct = channel tile][mt = edge tile]
#pragma unroll
    for (int ct = 0; ct < 4; ++ct)
#pragma unroll
        for (int mt = 0; mt < 4; ++mt) acc[ct][mt] = zero4;

    // GEMM (swapped): D[ch][edge] = sum_k W2[k][ch] * h1[edge][k]
#pragma unroll
    for (int ks = 0; ks < 4; ++ks) {
        const int kk = ks*32;
        bfrag8 wf[4], hf[4];
#pragma unroll
        for (int ct = 0; ct < 4; ++ct)
            wf[ct] = *(const bfrag8*)(Wf2 + ((size_t)((wc*4 + ct)*4 + ks)*64 + L)*8);
#pragma unroll
        for (int mt = 0; mt < 4; ++mt) {
            const int R = wr*64 + mt*16 + ln;
            hf[mt] = *(const bfrag8*)(lA + R*128 + swz_col(R, kk + q*8));
        }
#pragma unroll
        for (int ct = 0; ct < 4; ++ct)
#pragma unroll
            for (int mt = 0; mt < 4; ++mt)
                acc[ct][mt] = __builtin_amdgcn_mfma_f32_16x16x32_bf16(
                    wf[ct], hf[mt], acc[ct][mt], 0, 0, 0);
    }

    // epilogue: silu(acc + b2); packed 8B register->global stores; stats.
    {
        const size_t Rbase = ((size_t)bIdx*EE + (size_t)t*128) * 128;
#pragma unroll
        for (int ct = 0; ct < 4; ++ct) {
            const int ch0 = wc*64 + ct*16 + q*4;   // 4 consecutive channels
            float b4[4];
#pragma unroll
            for (int r = 0; r < 4; ++r) b4[r] = ld_g(b2g, ch0 + r, bf);
            float cs[4] = {0.f,0.f,0.f,0.f}, cq[4] = {0.f,0.f,0.f,0.f};
#pragma unroll
            for (int mt = 0; mt < 4; ++mt) {
                const int edge = wr*64 + mt*16 + ln;
                float v[4];
#pragma unroll
                for (int r = 0; r < 4; ++r) {
                    v[r] = silu_f(acc[ct][mt][r] + b4[r]);
                    cs[r] += v[r]; cq[r] += v[r]*v[r];
                }
                const size_t off = Rbase + (size_t)edge*128 + ch0;
                if (h2mode) {
                    bfrag4 pk;
#pragma unroll
                    for (int r = 0; r < 4; ++r) pk[r] = (bf16_t)v[r];
                    *(bfrag4*)(h2ws + off) = pk;
                } else if (bf) {
                    bfrag4 pk;
#pragma unroll
                    for (int r = 0; r < 4; ++r) pk[r] = (bf16_t)v[r];
                    *(bfrag4*)((bf16_t*)h2out + off) = pk;
                } else {
                    float4 f; f.x=v[0]; f.y=v[1]; f.z=v[2]; f.w=v[3];
                    *(float4*)((float*)h2out + off) = f;
                }
            }
            // reduce each channel's partial over the 16 ln lanes (64 edges/wave)
#pragma unroll
            for (int r = 0; r < 4; ++r) {
                float a = cs[r], b = cq[r];
                a += __shfl_xor(a, 1); a += __shfl_xor(a, 2);
                a += __shfl_xor(a, 4); a += __shfl_xor(a, 8);
                b += __shfl_xor(b, 1); b += __shfl_xor(b, 2);
                b += __shfl_xor(b, 4); b += __shfl_xor(b, 8);
                if (ln == 0) {
                    atomicAdd(&sSum[ch0 + r], a);
                    atomicAdd(&sQ[ch0 + r], b);
                }
            }
        }
    }
    __syncthreads();
    if (tid < 128) {
        atomicAdd(&totE[tid],       sSum[tid]);
        atomicAdd(&totE[128 + tid], sQ[tid]);
    }
}

// ---------------------------------------------------------------------------
// K4: derives edge-BN alpha/beta inline from totE, then mij = (h2*a+b)*em^2
// -> mij region (native dtype); h2 read from ws bf16 (h2mode) or in-place.
// Segment-sum -> inc. 8 ch/thread, 16 row-walkers.
// ---------------------------------------------------------------------------
__global__ __launch_bounds__(256)
void k_bn_scatter(void* __restrict__ dout,
                  const bf16_t* __restrict__ h2ws,
                  const void* __restrict__ emask,
                  const float* __restrict__ totE,
                  const void* __restrict__ g, const void* __restrict__ bt,
                  float* __restrict__ inc,
                  const int* __restrict__ flagp, int h2mode)
{
    const int bf = *flagp;
    void* mij = mij_ptr(dout, bf);
    const void* h2 = h2mode ? (const void*)h2ws : (const void*)mij;
    const int h2bf = h2mode | bf;
    const int bx = blockIdx.x;        // 4096 = B*N
    const int b  = bx >> 7, i = bx & 127;
    const int tid = threadIdx.x;
    const int cg = tid & 15, p = tid >> 4;   // 16 ch-groups x 16 row-walkers
    const int c0 = cg*8;
    float al[8], be[8];
#pragma unroll
    for (int j = 0; j < 8; ++j) {
        const int c = c0 + j;
        const float mn = totE[c] * (1.0f/ROWS_E);
        float vr = totE[128 + c] * (1.0f/ROWS_E) - mn*mn;
        vr = fmaxf(vr, 0.f);
        al[j] = ld_g(g, c, bf) * rsqrtf(vr + 1e-5f);
        be[j] = ld_g(bt, c, bf) - mn*al[j];
    }
    const size_t seg = (size_t)b*EE + (size_t)i*127;
    float s[8];
#pragma unroll
    for (int j = 0; j < 8; ++j) s[j] = 0.f;
    for (int e = p; e < 127; e += 16) {
        const float em  = ld_g(emask, seg + e, bf);
        const float em2 = em*em;
        const size_t base = (seg + e)*128 + c0;
        float v[8];
        if (h2bf) {
            const bfrag8 u = *(const bfrag8*)((const bf16_t*)h2 + base);
#pragma unroll
            for (int j = 0; j < 8; ++j) v[j] = (float)u[j];
        } else {
            const float4 f0 = *(const float4*)((const float*)h2 + base);
            const float4 f1 = *(const float4*)((const float*)h2 + base + 4);
            v[0]=f0.x; v[1]=f0.y; v[2]=f0.z; v[3]=f0.w;
            v[4]=f1.x; v[5]=f1.y; v[6]=f1.z; v[7]=f1.w;
        }
#pragma unroll
        for (int j = 0; j < 8; ++j) { v[j] = (v[j]*al[j] + be[j])*em2; s[j] += v[j]; }
        if (bf) {
            bfrag8 u;
#pragma unroll
            for (int j = 0; j < 8; ++j) u[j] = (bf16_t)v[j];
            *(bfrag8*)((bf16_t*)mij + base) = u;
        } else {
            float4 f0, f1;
            f0.x=v[0]; f0.y=v[1]; f0.z=v[2]; f0.w=v[3];
            f1.x=v[4]; f1.y=v[5]; f1.z=v[6]; f1.w=v[7];
            *(float4*)((float*)mij + base)     = f0;
            *(float4*)((float*)mij + base + 4) = f1;
        }
    }
    __shared__ float sm[16][128];
#pragma unroll
    for (int j = 0; j < 8; ++j) sm[p][c0+j] = s[j];
    __syncthreads();
    if (tid < 128) {
        float tsum = 0.f;
#pragma unroll
        for (int wk = 0; wk < 16; ++wk) tsum += sm[wk][tid];
        inc[(size_t)(b*NNODE + i)*HIDF + tid] = tsum * (1.0f/NNODE);
    }
}

// ---------------------------------------------------------------------------
// K5: node MLP (two 128x128 layers), 16 rows/block, BN partials
// ---------------------------------------------------------------------------
__global__ __launch_bounds__(128)
void k_node_mlp(const float* __restrict__ inc,
                const void* __restrict__ W1g, const void* __restrict__ b1g,
                const void* __restrict__ W2g, const void* __restrict__ b2g,
                float* __restrict__ h2n, float* __restrict__ partialN,
                const int* __restrict__ flagp)
{
    const int bf = *flagp;
    __shared__ float x[16][128];
    __shared__ float h[16][128];
    const int bx = blockIdx.x;   // 256
    const int tid = threadIdx.x; // 128
    const int r0 = bx*16;
    for (int r = 0; r < 16; ++r) x[r][tid] = inc[(size_t)(r0 + r)*128 + tid];
    __syncthreads();

    float a1[16];
#pragma unroll
    for (int r = 0; r < 16; ++r) a1[r] = 0.f;
#pragma unroll 8
    for (int k = 0; k < 128; ++k) {
        const float wv = ld_g(W1g, k*128 + tid, bf);
#pragma unroll
        for (int r = 0; r < 16; ++r) a1[r] += x[r][k]*wv;
    }
    const float bias1 = ld_g(b1g, tid, bf);
#pragma unroll
    for (int r = 0; r < 16; ++r) h[r][tid] = silu_f(a1[r] + bias1);
    __syncthreads();

    float a2[16];
#pragma unroll
    for (int r = 0; r < 16; ++r) a2[r] = 0.f;
#pragma unroll 8
    for (int k = 0; k < 128; ++k) {
        const float wv = ld_g(W2g, k*128 + tid, bf);
#pragma unroll
        for (int r = 0; r < 16; ++r) a2[r] += h[r][k]*wv;
    }
    const float bias2 = ld_g(b2g, tid, bf);
    float s = 0.f, sq = 0.f;
#pragma unroll
    for (int r = 0; r < 16; ++r) {
        const float v = silu_f(a2[r] + bias2);
        h2n[(size_t)(r0 + r)*128 + tid] = v;
        s += v; sq += v*v;
    }
    partialN[(size_t)bx*256 + tid]       = s;
    partialN[(size_t)bx*256 + 128 + tid] = sq;
}

// ---------------------------------------------------------------------------
// K7: final MLP: x=[nf, BN(h2n)*nmask] (192) -> 128 -> 64, BN partials.
// Node-BN alpha/beta derived inline from pN (folds old k_finalize_node).
// ---------------------------------------------------------------------------
__global__ __launch_bounds__(128)
void k_final_mlp(const void* __restrict__ nf,
                 const float* __restrict__ h2n, const float* __restrict__ pN,
                 const void* __restrict__ ng, const void* __restrict__ nbt,
                 const void* __restrict__ nmask,
                 const void* __restrict__ W1g, const void* __restrict__ b1g,
                 const void* __restrict__ W2g, const void* __restrict__ b2g,
                 float* __restrict__ hm, float* __restrict__ partialM,
                 const int* __restrict__ flagp)
{
    const int bf = *flagp;
    __shared__ float x[16][192];
    __shared__ float h[16][128];
    const int bx = blockIdx.x;   // 256
    const int tid = threadIdx.x; // 128
    const int r0 = bx*16;

    // inline node-BN finalize (each block redundantly reduces 256 partials)
    float sB = 0.f, qB = 0.f;
#pragma unroll 8
    for (int blk = 0; blk < 256; ++blk) { sB += pN[blk*256 + tid]; qB += pN[blk*256 + 128 + tid]; }
    const float mnN = sB / ROWS_N;
    float vrN = qB / ROWS_N - mnN*mnN;
    vrN = fmaxf(vrN, 0.f);
    const float an = ld_g(ng, tid, bf) * rsqrtf(vrN + 1e-5f);
    const float bn = ld_g(nbt, tid, bf) - mnN*an;

    for (int r = 0; r < 16; ++r) {
        const int row = r0 + r;
        const float mask = ld_g(nmask, row, bf);
        if (tid < 64) x[r][tid] = ld_g(nf, (size_t)row*INF + tid, bf);
        x[r][64 + tid] = (h2n[(size_t)row*128 + tid]*an + bn) * mask;
    }
    __syncthreads();

    float a1[16];
#pragma unroll
    for (int r = 0; r < 16; ++r) a1[r] = 0.f;
#pragma unroll 8
    for (int k = 0; k < 192; ++k) {
        const float wv = ld_g(W1g, k*128 + tid, bf);
#pragma unroll
        for (int r = 0; r < 16; ++r) a1[r] += x[r][k]*wv;
    }
    const float bias1 = ld_g(b1g, tid, bf);
#pragma unroll
    for (int r = 0; r < 16; ++r) h[r][tid] = silu_f(a1[r] + bias1);
    __syncthreads();

    if (tid < 64) {
        float a2[16];
#pragma unroll
        for (int r = 0; r < 16; ++r) a2[r] = 0.f;
#pragma unroll 8
        for (int k = 0; k < 128; ++k) {
            const float wv = ld_g(W2g, k*64 + tid, bf);
#pragma unroll
            for (int r = 0; r < 16; ++r) a2[r] += h[r][k]*wv;
        }
        const float bias2 = ld_g(b2g, tid, bf);
        float s = 0.f, sq = 0.f;
#pragma unroll
        for (int r = 0; r < 16; ++r) {
            const float v = silu_f(a2[r] + bias2);
            hm[(size_t)(r0 + r)*OUTF + tid] = v;
            s += v; sq += v*v;
        }
        partialM[(size_t)bx*128 + tid]      = s;
        partialM[(size_t)bx*128 + 64 + tid] = sq;
    }
}

// ---------------------------------------------------------------------------
// K9: out_node = BN(hm) * nodes_mask -> d_out[0 : B*N*OUT] (flag dtype).
// Final-BN alpha/beta derived inline from pM (folds old k_finalize_m).
// 256 blocks x 256 threads x 4 elems.
// ---------------------------------------------------------------------------
__global__ __launch_bounds__(256)
void k_out_node(const float* __restrict__ hm,
                const float* __restrict__ pM,
                const void* __restrict__ mg, const void* __restrict__ mbt,
                const void* __restrict__ nmask,
                void* __restrict__ dout,
                const int* __restrict__ flagp)
{
    const int bf = *flagp;
    const int tid = threadIdx.x;
    __shared__ float sab[128];
    if (tid < 64) {
        float s = 0.f, qv = 0.f;
#pragma unroll 8
        for (int blk = 0; blk < 256; ++blk) { s += pM[blk*128 + tid]; qv += pM[blk*128 + 64 + tid]; }
        const float mn = s / ROWS_N;
        float vr = qv / ROWS_N - mn*mn;
        vr = fmaxf(vr, 0.f);
        const float a = ld_g(mg, tid, bf) * rsqrtf(vr + 1e-5f);
        sab[tid]      = a;
        sab[64 + tid] = ld_g(mbt, tid, bf) - mn*a;
    }
    __syncthreads();
#pragma unroll
    for (int s = 0; s < 4; ++s) {
        const int idx = blockIdx.x*1024 + s*256 + tid;   // < 262144
        const int c = idx & 63;
        const int row = idx >> 6;
        const float v = (hm[idx]*sab[c] + sab[64 + c]) * ld_g(nmask, row, bf);
        st_g(dout, idx, v, bf);
    }
}

// ---------------------------------------------------------------------------
extern "C" void kernel_launch(void* const* d_in, const int* in_sizes, int n_in,
                              void* d_out, int out_size, void* d_ws, size_t ws_size,
                              hipStream_t stream)
{
    const void* nf    = d_in[0];
    const void* nmask = d_in[1];
    const void* emask = d_in[2];
    const void* eW1   = d_in[3];
    const void* eb1   = d_in[4];
    const void* eW2   = d_in[5];
    const void* eb2   = d_in[6];
    const void* eg    = d_in[7];
    const void* ebt   = d_in[8];
    const void* nW1   = d_in[9];
    const void* nb1   = d_in[10];
    const void* nW2   = d_in[11];
    const void* nb2   = d_in[12];
    const void* ng    = d_in[13];
    const void* nbt   = d_in[14];
    const void* mW1   = d_in[15];
    const void* mb1   = d_in[16];
    const void* mW2   = d_in[17];
    const void* mb2   = d_in[18];
    const void* mg    = d_in[19];
    const void* mbt   = d_in[20];

    // workspace layout (floats), ~9.7 MB base + optional 133 MB h2 buffer
    float* W    = (float*)d_ws;
    int*   flag = (int*)W;                       // [0,64)
    float* totE = W    + 64;                     // 256
    float* abE  = totE + 256;                    // 256 (unused, layout keep)
    float* inc  = abE  + 256;                    // 524288
    float* h2n  = inc  + 524288;                 // 524288
    float* pN   = h2n  + 524288;                 // 65536
    float* abN  = pN   + 65536;                  // 256 (unused, layout keep)
    float* hm   = abN  + 256;                    // 262144
    float* pM   = hm   + 262144;                 // 32768
    float* abM  = pM   + 32768;                  // 128 (unused, layout keep)
    bf16_t* Wf1 = (bf16_t*)(abM + 128);          // 16384 bf16 (32KB), 16B aligned
    bf16_t* Wf2 = Wf1 + 16384;                   // 16384 bf16 (32KB)
    float* Sbuf = (float*)(Wf2 + 16384);         // 524288 f32 (2MB)
    float* Rbuf = Sbuf + 524288;                 // 524288 f32 (2MB)
    bf16_t* h2ws = (bf16_t*)(Rbuf + 524288);     // optional 133 MB

    const size_t base_bytes = (size_t)((char*)h2ws - (char*)d_ws);
    const int h2mode = (ws_size >= base_bytes + H2_ELEMS*2 + 256) ? 1 : 0;

    k_prep<<<dim3(128), dim3(256), 0, stream>>>((const unsigned int*)eg, eW1, eW2, Wf1, Wf2, flag, totE);
    k_sr<<<dim3(32), dim3(256), 0, stream>>>(nf, Wf1, eb1, Sbuf, Rbuf, flag);
    k_edge_mlp<<<dim3(NBLK_EDGE), dim3(256), 0, stream>>>(Sbuf, Rbuf, Wf2, eb2, d_out, h2ws, flag, totE, h2mode);
    k_bn_scatter<<<dim3(BB*NNODE), dim3(256), 0, stream>>>(d_out, h2ws, emask, totE, eg, ebt, inc, flag, h2mode);
    k_node_mlp<<<dim3(256), dim3(128), 0, stream>>>(inc, nW1, nb1, nW2, nb2, h2n, pN, flag);
    k_final_mlp<<<dim3(256), dim3(128), 0, stream>>>(nf, h2n, pN, ng, nbt, nmask, mW1, mb1, mW2, mb2, hm, pM, flag);
    k_out_node<<<dim3(256), dim3(256), 0, stream>>>(hm, pM, mg, mbt, nmask, d_out, flag);
}

// Round 7
// 624.195 us; speedup vs baseline: 1.0262x; 1.0262x over previous
//
#include <hip/hip_runtime.h>
#include <hip/hip_bf16.h>

// Problem constants
#define BB    32
#define NNODE 128
#define INF   64
#define HIDF  128
#define OUTF  64
#define EE    (NNODE*(NNODE-1))   // 16256 edges per batch
#define TILES 127                  // 127 tiles of 128 edges per batch
#define NBLK_EDGE (BB*TILES)       // 4064
#define NBLK_N 512                 // node-MLP blocks (8 rows each)
#define ROWS_E 520192.0f
#define ROWS_N 4096.0f
#define OUT0_ELEMS (BB*NNODE*OUTF) // 262144
#define H2_ELEMS ((size_t)520192*128)

typedef __bf16 bf16_t;
typedef __bf16 bfrag8 __attribute__((ext_vector_type(8)));
typedef float  floatx4 __attribute__((ext_vector_type(4)));

// Dual-dtype helpers: bf=1 -> bf16 buffers, bf=0 -> fp32 buffers
__device__ __forceinline__ float ld_g(const void* p, size_t i, int bf) {
    return bf ? (float)((const bf16_t*)p)[i] : ((const float*)p)[i];
}
__device__ __forceinline__ void st_g(void* p, size_t i, float v, int bf) {
    if (bf) ((bf16_t*)p)[i] = (bf16_t)v; else ((float*)p)[i] = v;
}
__device__ __forceinline__ void* mij_ptr(void* dout, int bf) {
    return bf ? (void*)((bf16_t*)dout + OUT0_ELEMS)
              : (void*)((float*)dout + OUT0_ELEMS);
}
// silu without IEEE division: v_exp + v_add + v_rcp + v_mul.
__device__ __forceinline__ float silu_f(float x) {
    return x * __builtin_amdgcn_rcpf(1.0f + __expf(-x));
}

// LDS tile swizzles (16B-granule XOR involutions)
__device__ __forceinline__ int swz_col(int row, int col)  {   // 128-wide tile
    return col ^ ((row & 15) << 3);
}
__device__ __forceinline__ int swz64_col(int row, int col) {  // 64-wide tile
    return col ^ ((row & 7) << 3);
}

// ---------------------------------------------------------------------------
// K0: prep — detect dtype (eg ones: bf16 pair = 0x3F803F80), zero totE,
// pack W1/W2 into MFMA B-fragment order: line ((NB*4+ks)*4+q)*16+ln holds
// W[k=ks*32+q*8+j][n=NB*16+ln]; a wave (L=q*16+ln) reads one contiguous
// 1KB line per (NB,ks).
// ---------------------------------------------------------------------------
__global__ __launch_bounds__(256)
void k_prep(const unsigned int* __restrict__ eg_words,
            const void* __restrict__ W1g, const void* __restrict__ W2g,
            bf16_t* __restrict__ Wf1, bf16_t* __restrict__ Wf2,
            int* __restrict__ flag, float* __restrict__ totE)
{
    const int bf = (eg_words[0] == 0x3F803F80u) ? 1 : 0;
    if (blockIdx.x == 0) {
        if (threadIdx.x == 0) *flag = bf;
        totE[threadIdx.x] = 0.f;
    }
    const int idx = blockIdx.x*256 + threadIdx.x;   // 0..32767
    const int mat = idx >> 14;
    const int e   = idx & 16383;                    // e = k*128 + n
    const int n   = e & 127, k = e >> 7;
    const float v = ld_g(mat ? W2g : W1g, e, bf);
    const int NB = n >> 4, ln = n & 15;
    const int ks = k >> 5, q = (k >> 3) & 3, j = k & 7;
    bf16_t* dst = mat ? Wf2 : Wf1;
    dst[((((NB*4 + ks)*4 + q)*16 + ln) << 3) + j] = (bf16_t)v;
}

// ---------------------------------------------------------------------------
// K0c: per-node GEMM1 halves: S[n] = nf[n] @ W1[0:64] + b1,
//                             R[n] = nf[n] @ W1[64:128].
// ef@W1 = S[send]+R[recv]; fp32 outputs keep numerics identical.
// ---------------------------------------------------------------------------
__global__ __launch_bounds__(256)
void k_sr(const void* __restrict__ nf,
          const bf16_t* __restrict__ Wf1, const void* __restrict__ b1g,
          float* __restrict__ Sbuf, float* __restrict__ Rbuf,
          const int* __restrict__ flagp)
{
    __shared__ __align__(16) bf16_t lA[128*64];
    const int bf  = *flagp;
    const int r0  = blockIdx.x * 128;
    const int tid = threadIdx.x;

    // stage nf rows (swizzled, 8 granules/row)
#pragma unroll
    for (int s = 0; s < 4; ++s) {
        const int u = tid + s*256;            // 0..1023
        const int m = u >> 3;
        const int c = (u & 7) ^ (m & 7);
        const size_t gi = (size_t)(r0 + m)*INF + c*8;
        if (bf) {
            ((uint4*)lA)[u] = *(const uint4*)((const bf16_t*)nf + gi);
        } else {
            const float4 f0 = *(const float4*)((const float*)nf + gi);
            const float4 f1 = *(const float4*)((const float*)nf + gi + 4);
            bfrag8 v;
            v[0]=(bf16_t)f0.x; v[1]=(bf16_t)f0.y; v[2]=(bf16_t)f0.z; v[3]=(bf16_t)f0.w;
            v[4]=(bf16_t)f1.x; v[5]=(bf16_t)f1.y; v[6]=(bf16_t)f1.z; v[7]=(bf16_t)f1.w;
            *(bfrag8*)(lA + (size_t)u*8) = v;
        }
    }
    __syncthreads();

    const int w  = tid >> 6;
    const int L  = tid & 63;
    const int wr = w >> 1;
    const int wc = w & 1;
    const int q  = L >> 4;
    const int ln = L & 15;

    const floatx4 zero4 = {0.f, 0.f, 0.f, 0.f};
    floatx4 accS[4][4], accR[4][4];
#pragma unroll
    for (int mt = 0; mt < 4; ++mt)
#pragma unroll
        for (int nt = 0; nt < 4; ++nt) { accS[mt][nt] = zero4; accR[mt][nt] = zero4; }

#pragma unroll
    for (int ks = 0; ks < 2; ++ks) {
        bfrag8 af[4], bs[4], br[4];
#pragma unroll
        for (int mt = 0; mt < 4; ++mt) {
            const int Rr = wr*64 + mt*16 + ln;
            af[mt] = *(const bfrag8*)(lA + Rr*64 + swz64_col(Rr, ks*32 + q*8));
        }
#pragma unroll
        for (int nt = 0; nt < 4; ++nt) {
            bs[nt] = *(const bfrag8*)(Wf1 + ((size_t)((wc*4 + nt)*4 + ks)*64 + L)*8);
            br[nt] = *(const bfrag8*)(Wf1 + ((size_t)((wc*4 + nt)*4 + ks + 2)*64 + L)*8);
        }
#pragma unroll
        for (int mt = 0; mt < 4; ++mt)
#pragma unroll
            for (int nt = 0; nt < 4; ++nt) {
                accS[mt][nt] = __builtin_amdgcn_mfma_f32_16x16x32_bf16(
                    af[mt], bs[nt], accS[mt][nt], 0, 0, 0);
                accR[mt][nt] = __builtin_amdgcn_mfma_f32_16x16x32_bf16(
                    af[mt], br[nt], accR[mt][nt], 0, 0, 0);
            }
    }

#pragma unroll
    for (int nt = 0; nt < 4; ++nt) {
        const int col = wc*64 + nt*16 + ln;
        const float bias = ld_g(b1g, col, bf);
#pragma unroll
        for (int mt = 0; mt < 4; ++mt)
#pragma unroll
            for (int r = 0; r < 4; ++r) {
                const int row = wr*64 + mt*16 + q*4 + r;
                Sbuf[(size_t)(r0 + row)*128 + col] = accS[mt][nt][r] + bias;
                Rbuf[(size_t)(r0 + row)*128 + col] = accR[mt][nt][r];
            }
    }
}

// ---------------------------------------------------------------------------
// K1: edge MLP (R4-proven structure). h1 tile = silu(S[send]+R[recv]) -> LDS
// (swizzled); one MFMA GEMM (h2 = h1 @ W2) vs prepped Wf2 (L2); h2 staged
// back through LDS -> coalesced 16B/lane stores (bf16 ws if h2mode, else
// native). Edge-BN stats fused (shfl(16,32) + LDS atomics + 1 global
// atomic/ch/block). NOTE R5 lesson: register-direct C stores regressed
// (scattered 32B segments); keep the LDS-staged coalesced store.
// ---------------------------------------------------------------------------
__global__ __launch_bounds__(256, 4)
void k_edge_mlp(const float* __restrict__ Sbuf, const float* __restrict__ Rbuf,
                const bf16_t* __restrict__ Wf2, const void* __restrict__ b2g,
                void* __restrict__ dout, bf16_t* __restrict__ h2ws,
                const int* __restrict__ flagp, float* __restrict__ totE,
                int h2mode)
{
    __shared__ __align__(16) bf16_t lA[128*128];   // h1 (swz) -> h2 (swz)
    __shared__ float sSum[128], sQ[128];
    const int bf  = *flagp;
    void* h2out = mij_ptr(dout, bf);
    const int bx   = blockIdx.x;
    const int bIdx = bx / TILES;
    const int t    = bx - bIdx*TILES;
    const int tid  = threadIdx.x;

    if (tid < 128) { sSum[tid] = 0.f; sQ[tid] = 0.f; }

    // build h1 tile: granule u (row m, logical granule c) = silu(S+R)
    {
        const size_t nodeBase = (size_t)bIdx*NNODE*128;
#pragma unroll
        for (int s = 0; s < 8; ++s) {
            const int u = tid + s*256;              // 0..2047
            const int m = u >> 4;
            const int c = (u & 15) ^ (m & 15);
            const int eb = t*128 + m;
            const unsigned recv = ((unsigned)eb * 33027u) >> 22;   // eb/127
            const unsigned rr   = (unsigned)eb - recv*127u;
            const unsigned send = rr + (rr >= recv ? 1u : 0u);
            const float* Sp = Sbuf + nodeBase + (size_t)send*128 + c*8;
            const float* Rp = Rbuf + nodeBase + (size_t)recv*128 + c*8;
            const float4 s0 = *(const float4*)Sp;
            const float4 s1 = *(const float4*)(Sp + 4);
            const float4 r0v = *(const float4*)Rp;
            const float4 r1v = *(const float4*)(Rp + 4);
            bfrag8 v;
            v[0]=(bf16_t)silu_f(s0.x + r0v.x); v[1]=(bf16_t)silu_f(s0.y + r0v.y);
            v[2]=(bf16_t)silu_f(s0.z + r0v.z); v[3]=(bf16_t)silu_f(s0.w + r0v.w);
            v[4]=(bf16_t)silu_f(s1.x + r1v.x); v[5]=(bf16_t)silu_f(s1.y + r1v.y);
            v[6]=(bf16_t)silu_f(s1.z + r1v.z); v[7]=(bf16_t)silu_f(s1.w + r1v.w);
            *(bfrag8*)(lA + (size_t)u*8) = v;
        }
    }
    __syncthreads();

    const int w  = tid >> 6;
    const int L  = tid & 63;
    const int wr = w >> 1;
    const int wc = w & 1;
    const int q  = L >> 4;
    const int ln = L & 15;

    const floatx4 zero4 = {0.f, 0.f, 0.f, 0.f};
    floatx4 acc[4][4];
#pragma unroll
    for (int mt = 0; mt < 4; ++mt)
#pragma unroll
        for (int nt = 0; nt < 4; ++nt) acc[mt][nt] = zero4;

    // GEMM: h2 = h1 @ W2 (A from swizzled LDS, B from prepped global/L2)
#pragma unroll
    for (int ks = 0; ks < 4; ++ks) {
        const int kk = ks*32;
        bfrag8 af[4], bv[4];
#pragma unroll
        for (int mt = 0; mt < 4; ++mt) {
            const int R = wr*64 + mt*16 + ln;
            af[mt] = *(const bfrag8*)(lA + R*128 + swz_col(R, kk + q*8));
        }
#pragma unroll
        for (int nt = 0; nt < 4; ++nt)
            bv[nt] = *(const bfrag8*)(Wf2 + ((size_t)((wc*4 + nt)*4 + ks)*64 + L)*8);
#pragma unroll
        for (int mt = 0; mt < 4; ++mt)
#pragma unroll
            for (int nt = 0; nt < 4; ++nt)
                acc[mt][nt] = __builtin_amdgcn_mfma_f32_16x16x32_bf16(
                    af[mt], bv[nt], acc[mt][nt], 0, 0, 0);
    }
    __syncthreads();   // all lA reads done before epilogue overwrites it

    // epilogue: silu(acc + b2) -> lA (swizzled, bf16) + BN stats
#pragma unroll
    for (int nt = 0; nt < 4; ++nt) {
        const int col = wc*64 + nt*16 + ln;
        const float bias = ld_g(b2g, col, bf);
        float cs = 0.f, cq = 0.f;
#pragma unroll
        for (int mt = 0; mt < 4; ++mt)
#pragma unroll
            for (int r = 0; r < 4; ++r) {
                const int R = wr*64 + mt*16 + q*4 + r;
                const float v = silu_f(acc[mt][nt][r] + bias);
                cs += v; cq += v*v;
                lA[R*128 + swz_col(R, col)] = (bf16_t)v;
            }
        cs += __shfl_xor(cs, 16); cs += __shfl_xor(cs, 32);
        cq += __shfl_xor(cq, 16); cq += __shfl_xor(cq, 32);
        if (L < 16) { atomicAdd(&sSum[col], cs); atomicAdd(&sQ[col], cq); }
    }
    __syncthreads();

    // store 128x128 tile coalesced (granule un-swizzle; 16B/lane), flush stats
    {
        const size_t Rbase = ((size_t)bIdx*EE + (size_t)t*128) * 128;
#pragma unroll
        for (int s = 0; s < 8; ++s) {
            const int u = tid + s*256;
            const int m = u >> 4;
            const int c = (u & 15) ^ (m & 15);
            const size_t go = Rbase + (size_t)m*128 + c*8;
            if (h2mode) {
                *(uint4*)(h2ws + go) = ((const uint4*)lA)[u];
            } else if (bf) {
                *(uint4*)((bf16_t*)h2out + go) = ((const uint4*)lA)[u];
            } else {
                const bfrag8 vv = *(const bfrag8*)(lA + (size_t)u*8);
                float4 f0, f1;
                f0.x=(float)vv[0]; f0.y=(float)vv[1]; f0.z=(float)vv[2]; f0.w=(float)vv[3];
                f1.x=(float)vv[4]; f1.y=(float)vv[5]; f1.z=(float)vv[6]; f1.w=(float)vv[7];
                *(float4*)((float*)h2out + go)     = f0;
                *(float4*)((float*)h2out + go + 4) = f1;
            }
        }
        if (tid < 128) {
            atomicAdd(&totE[tid],       sSum[tid]);
            atomicAdd(&totE[128 + tid], sQ[tid]);
        }
    }
}

// ---------------------------------------------------------------------------
// K4: derives edge-BN alpha/beta inline from totE, then mij = (h2*a+b)*em^2
// -> mij region (native dtype); h2 read from ws bf16 (h2mode) or in-place.
// Segment-sum -> inc. 8 ch/thread, 16 row-walkers.
// ---------------------------------------------------------------------------
__global__ __launch_bounds__(256)
void k_bn_scatter(void* __restrict__ dout,
                  const bf16_t* __restrict__ h2ws,
                  const void* __restrict__ emask,
                  const float* __restrict__ totE,
                  const void* __restrict__ g, const void* __restrict__ bt,
                  float* __restrict__ inc,
                  const int* __restrict__ flagp, int h2mode)
{
    const int bf = *flagp;
    void* mij = mij_ptr(dout, bf);
    const void* h2 = h2mode ? (const void*)h2ws : (const void*)mij;
    const int h2bf = h2mode | bf;
    const int bx = blockIdx.x;        // 4096 = B*N
    const int b  = bx >> 7, i = bx & 127;
    const int tid = threadIdx.x;
    const int cg = tid & 15, p = tid >> 4;   // 16 ch-groups x 16 row-walkers
    const int c0 = cg*8;
    float al[8], be[8];
#pragma unroll
    for (int j = 0; j < 8; ++j) {
        const int c = c0 + j;
        const float mn = totE[c] * (1.0f/ROWS_E);
        float vr = totE[128 + c] * (1.0f/ROWS_E) - mn*mn;
        vr = fmaxf(vr, 0.f);
        al[j] = ld_g(g, c, bf) * rsqrtf(vr + 1e-5f);
        be[j] = ld_g(bt, c, bf) - mn*al[j];
    }
    const size_t seg = (size_t)b*EE + (size_t)i*127;
    float s[8];
#pragma unroll
    for (int j = 0; j < 8; ++j) s[j] = 0.f;
    for (int e = p; e < 127; e += 16) {
        const float em  = ld_g(emask, seg + e, bf);
        const float em2 = em*em;
        const size_t base = (seg + e)*128 + c0;
        float v[8];
        if (h2bf) {
            const bfrag8 u = *(const bfrag8*)((const bf16_t*)h2 + base);
#pragma unroll
            for (int j = 0; j < 8; ++j) v[j] = (float)u[j];
        } else {
            const float4 f0 = *(const float4*)((const float*)h2 + base);
            const float4 f1 = *(const float4*)((const float*)h2 + base + 4);
            v[0]=f0.x; v[1]=f0.y; v[2]=f0.z; v[3]=f0.w;
            v[4]=f1.x; v[5]=f1.y; v[6]=f1.z; v[7]=f1.w;
        }
#pragma unroll
        for (int j = 0; j < 8; ++j) { v[j] = (v[j]*al[j] + be[j])*em2; s[j] += v[j]; }
        if (bf) {
            bfrag8 u;
#pragma unroll
            for (int j = 0; j < 8; ++j) u[j] = (bf16_t)v[j];
            *(bfrag8*)((bf16_t*)mij + base) = u;
        } else {
            float4 f0, f1;
            f0.x=v[0]; f0.y=v[1]; f0.z=v[2]; f0.w=v[3];
            f1.x=v[4]; f1.y=v[5]; f1.z=v[6]; f1.w=v[7];
            *(float4*)((float*)mij + base)     = f0;
            *(float4*)((float*)mij + base + 4) = f1;
        }
    }
    __shared__ float sm[16][128];
#pragma unroll
    for (int j = 0; j < 8; ++j) sm[p][c0+j] = s[j];
    __syncthreads();
    if (tid < 128) {
        float tsum = 0.f;
#pragma unroll
        for (int wk = 0; wk < 16; ++wk) tsum += sm[wk][tid];
        inc[(size_t)(b*NNODE + i)*HIDF + tid] = tsum * (1.0f/NNODE);
    }
}

// ---------------------------------------------------------------------------
// K5: node MLP (two 128x128 layers), 8 rows/block (512 blocks -> 2 blk/CU),
// BN partials.
// ---------------------------------------------------------------------------
__global__ __launch_bounds__(128)
void k_node_mlp(const float* __restrict__ inc,
                const void* __restrict__ W1g, const void* __restrict__ b1g,
                const void* __restrict__ W2g, const void* __restrict__ b2g,
                float* __restrict__ h2n, float* __restrict__ partialN,
                const int* __restrict__ flagp)
{
    const int bf = *flagp;
    __shared__ float x[8][128];
    __shared__ float h[8][128];
    const int bx = blockIdx.x;   // 512
    const int tid = threadIdx.x; // 128
    const int r0 = bx*8;
    for (int r = 0; r < 8; ++r) x[r][tid] = inc[(size_t)(r0 + r)*128 + tid];
    __syncthreads();

    float a1[8];
#pragma unroll
    for (int r = 0; r < 8; ++r) a1[r] = 0.f;
#pragma unroll 8
    for (int k = 0; k < 128; ++k) {
        const float wv = ld_g(W1g, k*128 + tid, bf);
#pragma unroll
        for (int r = 0; r < 8; ++r) a1[r] += x[r][k]*wv;
    }
    const float bias1 = ld_g(b1g, tid, bf);
#pragma unroll
    for (int r = 0; r < 8; ++r) h[r][tid] = silu_f(a1[r] + bias1);
    __syncthreads();

    float a2[8];
#pragma unroll
    for (int r = 0; r < 8; ++r) a2[r] = 0.f;
#pragma unroll 8
    for (int k = 0; k < 128; ++k) {
        const float wv = ld_g(W2g, k*128 + tid, bf);
#pragma unroll
        for (int r = 0; r < 8; ++r) a2[r] += h[r][k]*wv;
    }
    const float bias2 = ld_g(b2g, tid, bf);
    float s = 0.f, sq = 0.f;
#pragma unroll
    for (int r = 0; r < 8; ++r) {
        const float v = silu_f(a2[r] + bias2);
        h2n[(size_t)(r0 + r)*128 + tid] = v;
        s += v; sq += v*v;
    }
    partialN[(size_t)bx*256 + tid]       = s;
    partialN[(size_t)bx*256 + 128 + tid] = sq;
}

// ---------------------------------------------------------------------------
// K7: final MLP: x=[nf, BN(h2n)*nmask] (192) -> 128 -> 64, 8 rows/block.
// Node-BN alpha/beta derived inline from pN (512 partial blocks).
// ---------------------------------------------------------------------------
__global__ __launch_bounds__(128)
void k_final_mlp(const void* __restrict__ nf,
                 const float* __restrict__ h2n, const float* __restrict__ pN,
                 const void* __restrict__ ng, const void* __restrict__ nbt,
                 const void* __restrict__ nmask,
                 const void* __restrict__ W1g, const void* __restrict__ b1g,
                 const void* __restrict__ W2g, const void* __restrict__ b2g,
                 float* __restrict__ hm, float* __restrict__ partialM,
                 const int* __restrict__ flagp)
{
    const int bf = *flagp;
    __shared__ float x[8][192];
    __shared__ float h[8][128];
    const int bx = blockIdx.x;   // 512
    const int tid = threadIdx.x; // 128
    const int r0 = bx*8;

    // inline node-BN finalize (each block redundantly reduces 512 partials)
    float sB = 0.f, qB = 0.f;
#pragma unroll 8
    for (int blk = 0; blk < NBLK_N; ++blk) { sB += pN[blk*256 + tid]; qB += pN[blk*256 + 128 + tid]; }
    const float mnN = sB / ROWS_N;
    float vrN = qB / ROWS_N - mnN*mnN;
    vrN = fmaxf(vrN, 0.f);
    const float an = ld_g(ng, tid, bf) * rsqrtf(vrN + 1e-5f);
    const float bn = ld_g(nbt, tid, bf) - mnN*an;

    for (int r = 0; r < 8; ++r) {
        const int row = r0 + r;
        const float mask = ld_g(nmask, row, bf);
        if (tid < 64) x[r][tid] = ld_g(nf, (size_t)row*INF + tid, bf);
        x[r][64 + tid] = (h2n[(size_t)row*128 + tid]*an + bn) * mask;
    }
    __syncthreads();

    float a1[8];
#pragma unroll
    for (int r = 0; r < 8; ++r) a1[r] = 0.f;
#pragma unroll 8
    for (int k = 0; k < 192; ++k) {
        const float wv = ld_g(W1g, k*128 + tid, bf);
#pragma unroll
        for (int r = 0; r < 8; ++r) a1[r] += x[r][k]*wv;
    }
    const float bias1 = ld_g(b1g, tid, bf);
#pragma unroll
    for (int r = 0; r < 8; ++r) h[r][tid] = silu_f(a1[r] + bias1);
    __syncthreads();

    if (tid < 64) {
        float a2[8];
#pragma unroll
        for (int r = 0; r < 8; ++r) a2[r] = 0.f;
#pragma unroll 8
        for (int k = 0; k < 128; ++k) {
            const float wv = ld_g(W2g, k*64 + tid, bf);
#pragma unroll
            for (int r = 0; r < 8; ++r) a2[r] += h[r][k]*wv;
        }
        const float bias2 = ld_g(b2g, tid, bf);
        float s = 0.f, sq = 0.f;
#pragma unroll
        for (int r = 0; r < 8; ++r) {
            const float v = silu_f(a2[r] + bias2);
            hm[(size_t)(r0 + r)*OUTF + tid] = v;
            s += v; sq += v*v;
        }
        partialM[(size_t)bx*128 + tid]      = s;
        partialM[(size_t)bx*128 + 64 + tid] = sq;
    }
}

// ---------------------------------------------------------------------------
// K9: out_node = BN(hm) * nodes_mask -> d_out[0 : B*N*OUT] (flag dtype).
// Final-BN alpha/beta derived inline from pM (512 partial blocks).
// ---------------------------------------------------------------------------
__global__ __launch_bounds__(256)
void k_out_node(const float* __restrict__ hm,
                const float* __restrict__ pM,
                const void* __restrict__ mg, const void* __restrict__ mbt,
                const void* __restrict__ nmask,
                void* __restrict__ dout,
                const int* __restrict__ flagp)
{
    const int bf = *flagp;
    const int tid = threadIdx.x;
    __shared__ float sab[128];
    if (tid < 64) {
        float s = 0.f, qv = 0.f;
#pragma unroll 8
        for (int blk = 0; blk < NBLK_N; ++blk) { s += pM[blk*128 + tid]; qv += pM[blk*128 + 64 + tid]; }
        const float mn = s / ROWS_N;
        float vr = qv / ROWS_N - mn*mn;
        vr = fmaxf(vr, 0.f);
        const float a = ld_g(mg, tid, bf) * rsqrtf(vr + 1e-5f);
        sab[tid]      = a;
        sab[64 + tid] = ld_g(mbt, tid, bf) - mn*a;
    }
    __syncthreads();
#pragma unroll
    for (int s = 0; s < 4; ++s) {
        const int idx = blockIdx.x*1024 + s*256 + tid;   // < 262144
        const int c = idx & 63;
        const int row = idx >> 6;
        const float v = (hm[idx]*sab[c] + sab[64 + c]) * ld_g(nmask, row, bf);
        st_g(dout, idx, v, bf);
    }
}

// ---------------------------------------------------------------------------
extern "C" void kernel_launch(void* const* d_in, const int* in_sizes, int n_in,
                              void* d_out, int out_size, void* d_ws, size_t ws_size,
                              hipStream_t stream)
{
    const void* nf    = d_in[0];
    const void* nmask = d_in[1];
    const void* emask = d_in[2];
    const void* eW1   = d_in[3];
    const void* eb1   = d_in[4];
    const void* eW2   = d_in[5];
    const void* eb2   = d_in[6];
    const void* eg    = d_in[7];
    const void* ebt   = d_in[8];
    const void* nW1   = d_in[9];
    const void* nb1   = d_in[10];
    const void* nW2   = d_in[11];
    const void* nb2   = d_in[12];
    const void* ng    = d_in[13];
    const void* nbt   = d_in[14];
    const void* mW1   = d_in[15];
    const void* mb1   = d_in[16];
    const void* mW2   = d_in[17];
    const void* mb2   = d_in[18];
    const void* mg    = d_in[19];
    const void* mbt   = d_in[20];

    // workspace layout (floats), ~10.5 MB base + optional 133 MB h2 buffer
    float* W    = (float*)d_ws;
    int*   flag = (int*)W;                       // [0,64)
    float* totE = W    + 64;                     // 256
    float* inc  = totE + 256;                    // 524288
    float* h2n  = inc  + 524288;                 // 524288
    float* pN   = h2n  + 524288;                 // 131072 (512*256)
    float* hm   = pN   + 131072;                 // 262144
    float* pM   = hm   + 262144;                 // 65536 (512*128)
    bf16_t* Wf1 = (bf16_t*)(pM + 65536);         // 16384 bf16 (32KB), 16B aligned
    bf16_t* Wf2 = Wf1 + 16384;                   // 16384 bf16 (32KB)
    float* Sbuf = (float*)(Wf2 + 16384);         // 524288 f32 (2MB)
    float* Rbuf = Sbuf + 524288;                 // 524288 f32 (2MB)
    bf16_t* h2ws = (bf16_t*)(Rbuf + 524288);     // optional 133 MB

    const size_t base_bytes = (size_t)((char*)h2ws - (char*)d_ws);
    const int h2mode = (ws_size >= base_bytes + H2_ELEMS*2 + 256) ? 1 : 0;

    k_prep<<<dim3(128), dim3(256), 0, stream>>>((const unsigned int*)eg, eW1, eW2, Wf1, Wf2, flag, totE);
    k_sr<<<dim3(32), dim3(256), 0, stream>>>(nf, Wf1, eb1, Sbuf, Rbuf, flag);
    k_edge_mlp<<<dim3(NBLK_EDGE), dim3(256), 0, stream>>>(Sbuf, Rbuf, Wf2, eb2, d_out, h2ws, flag, totE, h2mode);
    k_bn_scatter<<<dim3(BB*NNODE), dim3(256), 0, stream>>>(d_out, h2ws, emask, totE, eg, ebt, inc, flag, h2mode);
    k_node_mlp<<<dim3(NBLK_N), dim3(128), 0, stream>>>(inc, nW1, nb1, nW2, nb2, h2n, pN, flag);
    k_final_mlp<<<dim3(NBLK_N), dim3(128), 0, stream>>>(nf, h2n, pN, ng, nbt, nmask, mW1, mb1, mW2, mb2, hm, pM, flag);
    k_out_node<<<dim3(256), dim3(256), 0, stream>>>(hm, pM, mg, mbt, nmask, d_out, flag);
}